// Round 2
// baseline (1059.740 us; speedup 1.0000x reference)
//
#include <hip/hip_runtime.h>

// ---------------------------------------------------------------------------
// MatchNetAssign: 65536x128 pairs -> MLP(6->64->32->1) -> sigmoid -> clamp<0.5
// -> per-target top-8 -> reorder by argsort(-targets[:,1], stable).
// ROUND 2: controlled experiment. K1 is now an EXACT f32 VALU MLP (no MFMA)
// writing bf16 logits; K2/K3/K4 unchanged from round 1 (MARGIN 0.75->0.0625,
// covers only the bf16 storage truncation now). Pass => round-1 bug was the
// MFMA fragment mapping. Fail => bug is in selection/ordering/output format.
// ---------------------------------------------------------------------------

typedef unsigned int   u32;
typedef unsigned short u16;

#define N_PROP   65536
#define N_TGT    128
#define N_PAIR   (N_PROP * N_TGT)      // 8388608
#define CAP      2048
#define MARGIN   0.0625f

static __device__ __forceinline__ float bf2f(u16 u) {
  return __uint_as_float(((u32)u) << 16);
}

// ---------------------------------------------------------------------------
// K1: exact f32 logits for all pairs. One thread per pair (flat = n*128 + t).
// Weight indices are compile-time constants -> uniform s_load -> scalar
// operands on v_fma_f32 (no LDS round-trip, no per-lane weight loads).
// Sigmoid is monotone so we store the LOGIT (bf16-truncated) for ranking.
// ---------------------------------------------------------------------------
__global__ __launch_bounds__(256) void k1_exact(
    const float* __restrict__ p_th, const float* __restrict__ p_xy,
    const float* __restrict__ p_di, const float* __restrict__ p_po,
    const float* __restrict__ p_ne, const float* __restrict__ p_io,
    const float* __restrict__ W1, const float* __restrict__ b1,
    const float* __restrict__ W2, const float* __restrict__ b2,
    const float* __restrict__ W3, const float* __restrict__ b3,
    u16* __restrict__ lgout)
{
  const int idx = blockIdx.x * 256 + threadIdx.x;   // flat pair index

  float f[6];
  f[0] = 1.0f - fminf(p_th[idx], 180.0f) / 180.0f;
  f[1] = 1.0f - fminf(p_xy[idx], 800.0f) / 800.0f;
  f[2] = 1.0f - fminf(p_di[idx], 800.0f) / 800.0f;
  f[3] = p_po[idx];
  f[4] = p_ne[idx];
  f[5] = p_io[idx];

  float h1[64];
#pragma unroll
  for (int j = 0; j < 64; ++j) {
    float s = b1[j];
#pragma unroll
    for (int k = 0; k < 6; ++k) s = fmaf(f[k], W1[k * 64 + j], s);
    h1[j] = fmaxf(s, 0.0f);
  }
  float h2[32];
#pragma unroll
  for (int j = 0; j < 32; ++j) {
    float s = b2[j];
#pragma unroll
    for (int k = 0; k < 64; ++k) s = fmaf(h1[k], W2[k * 32 + j], s);
    h2[j] = fmaxf(s, 0.0f);
  }
  float lo = b3[0];
#pragma unroll
  for (int k = 0; k < 32; ++k) lo = fmaf(h2[k], W3[k], lo);

  lgout[idx] = (u16)(__float_as_uint(lo) >> 16);    // bf16 truncate
}

// ---------------------------------------------------------------------------
// K2a: per-(chunk, target) top-8 approx values. 256 blocks x 128 threads,
// each block covers 256 n rows; thread t tracks its target's top-8.
// ---------------------------------------------------------------------------
__global__ void k2a_part(const u16* __restrict__ lg, float* __restrict__ pval)
{
  const int t = threadIdx.x;       // 0..127
  const int c = blockIdx.x;        // 0..255
  const size_t base = (size_t)c * 256 * 128 + t;
  float v[8];
#pragma unroll
  for (int q = 0; q < 8; ++q) v[q] = -3.4e38f;
#pragma unroll 4
  for (int i = 0; i < 256; ++i) {
    const float x = bf2f(lg[base + (size_t)i * 128]);
    if (x > v[7]) {
      int k = 7;
      while (k > 0 && x > v[k - 1]) { v[k] = v[k - 1]; --k; }
      v[k] = x;
    }
  }
  float* o = pval + ((size_t)c * 128 + t) * 8;
#pragma unroll
  for (int q = 0; q < 8; ++q) o[q] = v[q];
}

// K2b: merge 256 partials per target -> tau[t] = (8th approx) - MARGIN.
__global__ void k2b_merge(const float* __restrict__ pval, float* __restrict__ tau)
{
  __shared__ float sm[64 * 8];
  const int t = blockIdx.x;
  const int i = threadIdx.x;       // 0..63
  float v[8];
#pragma unroll
  for (int q = 0; q < 8; ++q) v[q] = -3.4e38f;
  for (int e = i; e < 2048; e += 64) {
    const float x = pval[(size_t)(e >> 3) * 1024 + (size_t)t * 8 + (e & 7)];
    if (x > v[7]) {
      int k = 7;
      while (k > 0 && x > v[k - 1]) { v[k] = v[k - 1]; --k; }
      v[k] = x;
    }
  }
#pragma unroll
  for (int q = 0; q < 8; ++q) sm[i * 8 + q] = v[q];
  __syncthreads();
  if (i == 0) {
    float w[8];
#pragma unroll
    for (int q = 0; q < 8; ++q) w[q] = -3.4e38f;
    for (int e = 0; e < 512; ++e) {
      const float x = sm[e];
      if (x > w[7]) {
        int k = 7;
        while (k > 0 && x > w[k - 1]) { w[k] = w[k - 1]; --k; }
        w[k] = x;
      }
    }
    tau[t] = w[7] - MARGIN;
  }
}

// K2c: collect candidates: approx >= tau, plus forced n<16 (zero-fill ties).
__global__ void k2c_cand(const u16* __restrict__ lg, const float* __restrict__ tau,
                         int* __restrict__ cnt, int* __restrict__ cand)
{
  const int t = threadIdx.x;
  const int c = blockIdx.x;
  const int n0 = c * 256;
  const float ta = tau[t];
  for (int i = 0; i < 256; ++i) {
    const int n = n0 + i;
    const float x = bf2f(lg[(size_t)n * 128 + t]);
    if (x >= ta || n < 16) {
      const int p = atomicAdd(&cnt[t], 1);
      if (p < CAP) cand[(size_t)t * CAP + p] = n;
    }
  }
}

// ---------------------------------------------------------------------------
// K3: exact f32 refine of candidates + per-target top-8 with exact ref
// semantics: key = (sigmoid < 0.5 ? 0 : sigmoid), order (key desc, idx asc).
// ---------------------------------------------------------------------------
__global__ __launch_bounds__(256) void k3_refine(
    const float* __restrict__ p_th, const float* __restrict__ p_xy,
    const float* __restrict__ p_di, const float* __restrict__ p_po,
    const float* __restrict__ p_ne, const float* __restrict__ p_io,
    const float* __restrict__ W1, const float* __restrict__ b1,
    const float* __restrict__ W2, const float* __restrict__ b2,
    const float* __restrict__ W3, const float* __restrict__ b3,
    const int* __restrict__ cnt, const int* __restrict__ cand,
    int* __restrict__ t8i, float* __restrict__ t8k)
{
  __shared__ float wl[2561];
  __shared__ float ck[CAP];
  __shared__ int   cnid[CAP];
  const int t = blockIdx.x;
  const int tid = threadIdx.x;

  for (int i = tid; i < 2561; i += 256) {
    float x;
    if (i < 384)       x = W1[i];
    else if (i < 448)  x = b1[i - 384];
    else if (i < 2496) x = W2[i - 448];
    else if (i < 2528) x = b2[i - 2496];
    else if (i < 2560) x = W3[i - 2528];
    else               x = b3[0];
    wl[i] = x;
  }
  __syncthreads();
  const float* W1L = wl;
  const float* b1L = wl + 384;
  const float* W2L = wl + 448;
  const float* b2L = wl + 2496;
  const float* W3L = wl + 2528;
  const float  b3s = wl[2560];

  int m = cnt[t];
  if (m > CAP) m = CAP;

  for (int i = tid; i < m; i += 256) {
    const int n = cand[(size_t)t * CAP + i];
    const size_t off = (size_t)n * 128 + t;
    float f[6];
    f[0] = 1.0f - fminf(p_th[off], 180.0f) / 180.0f;
    f[1] = 1.0f - fminf(p_xy[off], 800.0f) / 800.0f;
    f[2] = 1.0f - fminf(p_di[off], 800.0f) / 800.0f;
    f[3] = p_po[off]; f[4] = p_ne[off]; f[5] = p_io[off];

    float h1[64];
#pragma unroll
    for (int j = 0; j < 64; ++j) {
      float s = b1L[j];
#pragma unroll
      for (int k = 0; k < 6; ++k) s = fmaf(f[k], W1L[k * 64 + j], s);
      h1[j] = fmaxf(s, 0.0f);
    }
    float h2[32];
#pragma unroll
    for (int j = 0; j < 32; ++j) {
      float s = b2L[j];
#pragma unroll
      for (int k = 0; k < 64; ++k) s = fmaf(h1[k], W2L[k * 32 + j], s);
      h2[j] = fmaxf(s, 0.0f);
    }
    float lo = b3s;
#pragma unroll
    for (int k = 0; k < 32; ++k) lo = fmaf(h2[k], W3L[k], lo);
    const float sg = 1.0f / (1.0f + expf(-lo));
    ck[i]   = (sg < 0.5f) ? 0.0f : sg;
    cnid[i] = n;
  }
  __syncthreads();

  if (tid == 0) {
    float bv[8]; int bi[8];
#pragma unroll
    for (int q = 0; q < 8; ++q) { bv[q] = -1.0f; bi[q] = 0x7fffffff; }
    for (int i = 0; i < m; ++i) {
      const float x = ck[i];
      const int   n = cnid[i];
      if (x > bv[7] || (x == bv[7] && n < bi[7])) {
        int k = 7;
        while (k > 0 && (x > bv[k - 1] || (x == bv[k - 1] && n < bi[k - 1]))) {
          bv[k] = bv[k - 1]; bi[k] = bi[k - 1]; --k;
        }
        bv[k] = x; bi[k] = n;
      }
    }
#pragma unroll
    for (int q = 0; q < 8; ++q) {
      t8i[t * 8 + q] = bi[q];
      t8k[t * 8 + q] = bv[q];
    }
  }
}

// ---------------------------------------------------------------------------
// K4: order = stable descending argsort of targets[:,1]; assemble outputs.
// d_out (int32): rows[1024] | cols[1024] | valid[1024]
// ---------------------------------------------------------------------------
__global__ void k4_final(const float* __restrict__ targets,
                         const int* __restrict__ t8i, const float* __restrict__ t8k,
                         int* __restrict__ out)
{
  __shared__ float key[128];
  __shared__ int   ord[128];
  const int i = threadIdx.x;    // 0..127
  key[i] = targets[i * 4 + 1];
  __syncthreads();
  const float ki = key[i];
  int r = 0;
  for (int j = 0; j < 128; ++j) {
    const float kj = key[j];
    r += (kj > ki) || (kj == ki && j < i);
  }
  ord[r] = i;
  __syncthreads();
  const int src = ord[i];
#pragma unroll
  for (int k = 0; k < 8; ++k) {
    out[i * 8 + k]        = t8i[src * 8 + k];
    out[1024 + i * 8 + k] = src;
    out[2048 + i * 8 + k] = (t8k[src * 8 + k] > 0.0f) ? 1 : 0;
  }
}

// ---------------------------------------------------------------------------
extern "C" void kernel_launch(void* const* d_in, const int* in_sizes, int n_in,
                              void* d_out, int out_size, void* d_ws, size_t ws_size,
                              hipStream_t stream)
{
  const float* p_th = (const float*)d_in[0];
  const float* p_xy = (const float*)d_in[1];
  const float* p_di = (const float*)d_in[2];
  const float* p_po = (const float*)d_in[3];
  const float* p_ne = (const float*)d_in[4];
  const float* p_io = (const float*)d_in[5];
  const float* tgt  = (const float*)d_in[6];
  const float* W1   = (const float*)d_in[7];
  const float* b1   = (const float*)d_in[8];
  const float* W2   = (const float*)d_in[9];
  const float* b2   = (const float*)d_in[10];
  const float* W3   = (const float*)d_in[11];
  const float* b3   = (const float*)d_in[12];

  // workspace carve (needs ~18.9 MB)
  char* base = (char*)d_ws;
  u16*   lg   = (u16*)  (base);                 // 16,777,216 B
  float* pval = (float*)(base + 16777216);      //  1,048,576 B
  float* tau  = (float*)(base + 17825792);      //        512 B
  int*   cnt  = (int*)  (base + 17826304);      //        512 B
  int*   cand = (int*)  (base + 17826816);      //  1,048,576 B
  int*   t8i  = (int*)  (base + 18875392);      //      4,096 B
  float* t8k  = (float*)(base + 18879488);      //      4,096 B

  hipMemsetAsync(cnt, 0, 128 * sizeof(int), stream);

  k1_exact<<<N_PAIR / 256, 256, 0, stream>>>(p_th, p_xy, p_di, p_po, p_ne, p_io,
                                             W1, b1, W2, b2, W3, b3, lg);
  k2a_part<<<256, 128, 0, stream>>>(lg, pval);
  k2b_merge<<<128, 64, 0, stream>>>(pval, tau);
  k2c_cand<<<256, 128, 0, stream>>>(lg, tau, cnt, cand);
  k3_refine<<<128, 256, 0, stream>>>(p_th, p_xy, p_di, p_po, p_ne, p_io,
                                     W1, b1, W2, b2, W3, b3,
                                     cnt, cand, t8i, t8k);
  k4_final<<<1, 128, 0, stream>>>(tgt, t8i, t8k, (int*)d_out);
}

// Round 4
// 823.668 us; speedup vs baseline: 1.2866x; 1.2866x over previous
//
#include <hip/hip_runtime.h>

// ---------------------------------------------------------------------------
// MatchNetAssign: 65536x128 pairs -> MLP(6->64->32->1) -> sigmoid -> clamp<0.5
// -> per-target top-8 -> reorder by argsort(-targets[:,1], stable).
// ROUND 4: two fixes vs the round-3 failure:
//  (1) MARGIN 0.75 -> 0.15 and CAP 2048 -> 4096: rounds 1/3 plausibly failed
//      from K2c candidate-buffer overflow (silent drops of true top-8), which
//      round 2 (margin 0.0625, passed) never hit. Error budget: bf16-h1 trunc
//      + W2-RNE + logit-store trunc ~ 0.02-0.05 << 0.15.
//  (2) K1 uses 16x16x32 MFMA whose A (m89), B (m120), C/D (m89/m91) layouts
//      are ALL HW-verified, with ZERO pre-MFMA cross-lane exchange: lane
//      (q,lo4) computes exactly the h1 units (k = 32c+8q+j) of pair lo4 that
//      its own B-fragment needs. L1 still computed once per pair (split
//      across quads). Only cross-lane op: final butterfly over quads.
// K2..K4 frozen from the round-2 PASSING pipeline (CAP constant aside).
// ---------------------------------------------------------------------------

typedef unsigned int   u32;
typedef unsigned short u16;
typedef short s8v  __attribute__((ext_vector_type(8)));   // 8 bf16 = 4 VGPR
typedef float f4v  __attribute__((ext_vector_type(4)));   // 16x16 accum

#define N_PROP   65536
#define N_TGT    128
#define N_PAIR   (N_PROP * N_TGT)      // 8388608
#define CAP      4096
#define MARGIN   0.15f

static __device__ __forceinline__ u32 packbf(float a, float b) {
  // low16 = bf16_trunc(a), high16 = bf16_trunc(b)  (single v_perm_b32)
  return __builtin_amdgcn_perm(__float_as_uint(b), __float_as_uint(a), 0x07060302u);
}
static __device__ __forceinline__ float bf16_rne(float x) {
  u32 u = __float_as_uint(x);
  u = u + 0x7fffu + ((u >> 16) & 1u);
  return __uint_as_float(u & 0xffff0000u);
}
static __device__ __forceinline__ float bf2f(u16 u) {
  return __uint_as_float(((u32)u) << 16);
}
static __device__ __forceinline__ s8v mk_frag(u32 a, u32 b, u32 c, u32 d) {
  union { u32 u[4]; s8v v; } x;
  x.u[0] = a; x.u[1] = b; x.u[2] = c; x.u[3] = d;
  return x.v;
}
static __device__ __forceinline__ f4v MF16(s8v a, s8v b, f4v c) {
  return __builtin_amdgcn_mfma_f32_16x16x32_bf16(a, b, c, 0, 0, 0);
}

// ---------------------------------------------------------------------------
// K1: 16 pairs per wave-iteration. Lane (q = l>>4, lo4 = l&15):
//  - computes h1 units {32c+8q+j, c=0..1, j=0..7} of pair (g*16+lo4) exactly
//    in f32 from preloaded per-lane W1 row slices, truncates to bf16 pairs.
//    This IS the B-fragment: B[k=8q+j][n=lo4] = h1[pair lo4][32c+8q+j].
//  - A-frags = W2^T, aw[mt][c] element j = W2[(32c+8q+j)*32 + 16mt+lo4].
//  - 4 MFMAs (2 m-tiles x 2 k-chunks). C/D: col=lo4(pair), row=4q+r (+16mt).
//  - L3: per-lane partial dot W3.relu(h2+b2) over its 8 rows, butterfly over
//    quads (shfl_xor 16, 32), q==0 writes bf16 logit.
// ---------------------------------------------------------------------------
__global__ __launch_bounds__(256) void k1_mfma(
    const float* __restrict__ p_th, const float* __restrict__ p_xy,
    const float* __restrict__ p_di, const float* __restrict__ p_po,
    const float* __restrict__ p_ne, const float* __restrict__ p_io,
    const float* __restrict__ W1, const float* __restrict__ b1,
    const float* __restrict__ W2, const float* __restrict__ b2,
    const float* __restrict__ W3, const float* __restrict__ b3,
    u16* __restrict__ lgout)
{
  const int tid = threadIdx.x;
  const int l   = tid & 63;
  const int lo4 = l & 15;
  const int q   = (l >> 4) & 3;

  // ---- per-lane W1 row slices (units 32c+8q+j), f32 for exact L1 ----
  float w1r[2][6][8];
  float b1v[2][8];
#pragma unroll
  for (int c = 0; c < 2; ++c) {
#pragma unroll
    for (int k = 0; k < 6; ++k) {
      const float4 lo = *(const float4*)(W1 + k * 64 + 32 * c + 8 * q);
      const float4 hi = *(const float4*)(W1 + k * 64 + 32 * c + 8 * q + 4);
      w1r[c][k][0] = lo.x; w1r[c][k][1] = lo.y; w1r[c][k][2] = lo.z; w1r[c][k][3] = lo.w;
      w1r[c][k][4] = hi.x; w1r[c][k][5] = hi.y; w1r[c][k][6] = hi.z; w1r[c][k][7] = hi.w;
    }
    const float4 blo = *(const float4*)(b1 + 32 * c + 8 * q);
    const float4 bhi = *(const float4*)(b1 + 32 * c + 8 * q + 4);
    b1v[c][0] = blo.x; b1v[c][1] = blo.y; b1v[c][2] = blo.z; b1v[c][3] = blo.w;
    b1v[c][4] = bhi.x; b1v[c][5] = bhi.y; b1v[c][6] = bhi.z; b1v[c][7] = bhi.w;
  }

  // ---- A-frags: W2^T, m-tile mt (j2 16mt..16mt+15), k-chunk c ----
  s8v aw[2][2];
#pragma unroll
  for (int mt = 0; mt < 2; ++mt)
#pragma unroll
    for (int c = 0; c < 2; ++c) {
      float v[8];
#pragma unroll
      for (int j = 0; j < 8; ++j)
        v[j] = bf16_rne(W2[(32 * c + 8 * q + j) * 32 + 16 * mt + lo4]);
      aw[mt][c] = mk_frag(packbf(v[0], v[1]), packbf(v[2], v[3]),
                          packbf(v[4], v[5]), packbf(v[6], v[7]));
    }

  // ---- per-lane b2/W3 rows from C/D mapping ----
  float b2l[2][4], w3l[2][4];
#pragma unroll
  for (int mt = 0; mt < 2; ++mt)
#pragma unroll
    for (int r = 0; r < 4; ++r) {
      const int row = 16 * mt + 4 * q + r;
      b2l[mt][r] = b2[row];
      w3l[mt][r] = W3[row];
    }
  const float b3s = b3[0];
  const f4v Z4 = {};

  const int nwaves = (gridDim.x * blockDim.x) >> 6;      // 8192
  const int w0 = (blockIdx.x * blockDim.x + tid) >> 6;
  const int NGRP = N_PAIR / 16;                          // 524288

  for (int g = w0; g < NGRP; g += nwaves) {
    const int idx = g * 16 + lo4;                        // this lane's pair
    const float x0 = p_th[idx], x1 = p_xy[idx], x2 = p_di[idx];
    float f[6];
    f[0] = fmaf(fminf(x0, 180.0f), -(1.0f / 180.0f), 1.0f);
    f[1] = fmaf(fminf(x1, 800.0f), -(1.0f / 800.0f), 1.0f);
    f[2] = fmaf(fminf(x2, 800.0f), -(1.0f / 800.0f), 1.0f);
    f[3] = p_po[idx]; f[4] = p_ne[idx]; f[5] = p_io[idx];

    // ---- L1 exact (this lane's 16 h1 units) -> bf16 B-frags ----
    u32 hb[2][4];
#pragma unroll
    for (int c = 0; c < 2; ++c)
#pragma unroll
      for (int j = 0; j < 8; j += 2) {
        float s0 = b1v[c][j], s1 = b1v[c][j + 1];
#pragma unroll
        for (int k = 0; k < 6; ++k) {
          s0 = fmaf(f[k], w1r[c][k][j], s0);
          s1 = fmaf(f[k], w1r[c][k][j + 1], s1);
        }
        hb[c][j >> 1] = packbf(fmaxf(s0, 0.0f), fmaxf(s1, 0.0f));
      }
    const s8v bf0 = mk_frag(hb[0][0], hb[0][1], hb[0][2], hb[0][3]);
    const s8v bf1 = mk_frag(hb[1][0], hb[1][1], hb[1][2], hb[1][3]);

    // ---- L2: h2^T = W2^T . h1^T  (2 m-tiles x 2 k-chunks) ----
    f4v acc0 = Z4, acc1 = Z4;
    acc0 = MF16(aw[0][0], bf0, acc0);
    acc0 = MF16(aw[0][1], bf1, acc0);
    acc1 = MF16(aw[1][0], bf0, acc1);
    acc1 = MF16(aw[1][1], bf1, acc1);

    // ---- L3: partial dot over this lane's 8 h2 rows, butterfly over quads --
    float part = 0.0f;
#pragma unroll
    for (int r = 0; r < 4; ++r) {
      part = fmaf(w3l[0][r], fmaxf(acc0[r] + b2l[0][r], 0.0f), part);
      part = fmaf(w3l[1][r], fmaxf(acc1[r] + b2l[1][r], 0.0f), part);
    }
    part += __shfl_xor(part, 16, 64);
    part += __shfl_xor(part, 32, 64);

    if (q == 0)
      lgout[idx] = (u16)(__float_as_uint(part + b3s) >> 16);
  }
}

// ---------------------------------------------------------------------------
// K2a: per-(chunk, target) top-8 approx values. 256 blocks x 128 threads,
// each block covers 256 n rows; thread t tracks its target's top-8.
// ---------------------------------------------------------------------------
__global__ void k2a_part(const u16* __restrict__ lg, float* __restrict__ pval)
{
  const int t = threadIdx.x;       // 0..127
  const int c = blockIdx.x;        // 0..255
  const size_t base = (size_t)c * 256 * 128 + t;
  float v[8];
#pragma unroll
  for (int q = 0; q < 8; ++q) v[q] = -3.4e38f;
#pragma unroll 4
  for (int i = 0; i < 256; ++i) {
    const float x = bf2f(lg[base + (size_t)i * 128]);
    if (x > v[7]) {
      int k = 7;
      while (k > 0 && x > v[k - 1]) { v[k] = v[k - 1]; --k; }
      v[k] = x;
    }
  }
  float* o = pval + ((size_t)c * 128 + t) * 8;
#pragma unroll
  for (int q = 0; q < 8; ++q) o[q] = v[q];
}

// K2b: merge 256 partials per target -> tau[t] = (8th approx) - MARGIN.
__global__ void k2b_merge(const float* __restrict__ pval, float* __restrict__ tau)
{
  __shared__ float sm[64 * 8];
  const int t = blockIdx.x;
  const int i = threadIdx.x;       // 0..63
  float v[8];
#pragma unroll
  for (int q = 0; q < 8; ++q) v[q] = -3.4e38f;
  for (int e = i; e < 2048; e += 64) {
    const float x = pval[(size_t)(e >> 3) * 1024 + (size_t)t * 8 + (e & 7)];
    if (x > v[7]) {
      int k = 7;
      while (k > 0 && x > v[k - 1]) { v[k] = v[k - 1]; --k; }
      v[k] = x;
    }
  }
#pragma unroll
  for (int q = 0; q < 8; ++q) sm[i * 8 + q] = v[q];
  __syncthreads();
  if (i == 0) {
    float w[8];
#pragma unroll
    for (int q = 0; q < 8; ++q) w[q] = -3.4e38f;
    for (int e = 0; e < 512; ++e) {
      const float x = sm[e];
      if (x > w[7]) {
        int k = 7;
        while (k > 0 && x > w[k - 1]) { w[k] = w[k - 1]; --k; }
        w[k] = x;
      }
    }
    tau[t] = w[7] - MARGIN;
  }
}

// K2c: collect candidates: approx >= tau, plus forced n<16 (zero-fill ties).
__global__ void k2c_cand(const u16* __restrict__ lg, const float* __restrict__ tau,
                         int* __restrict__ cnt, int* __restrict__ cand)
{
  const int t = threadIdx.x;
  const int c = blockIdx.x;
  const int n0 = c * 256;
  const float ta = tau[t];
  for (int i = 0; i < 256; ++i) {
    const int n = n0 + i;
    const float x = bf2f(lg[(size_t)n * 128 + t]);
    if (x >= ta || n < 16) {
      const int p = atomicAdd(&cnt[t], 1);
      if (p < CAP) cand[(size_t)t * CAP + p] = n;
    }
  }
}

// ---------------------------------------------------------------------------
// K3: exact f32 refine of candidates + per-target top-8 with exact ref
// semantics: key = (sigmoid < 0.5 ? 0 : sigmoid), order (key desc, idx asc).
// ---------------------------------------------------------------------------
__global__ __launch_bounds__(256) void k3_refine(
    const float* __restrict__ p_th, const float* __restrict__ p_xy,
    const float* __restrict__ p_di, const float* __restrict__ p_po,
    const float* __restrict__ p_ne, const float* __restrict__ p_io,
    const float* __restrict__ W1, const float* __restrict__ b1,
    const float* __restrict__ W2, const float* __restrict__ b2,
    const float* __restrict__ W3, const float* __restrict__ b3,
    const int* __restrict__ cnt, const int* __restrict__ cand,
    int* __restrict__ t8i, float* __restrict__ t8k)
{
  __shared__ float wl[2561];
  __shared__ float ck[CAP];
  __shared__ int   cnid[CAP];
  const int t = blockIdx.x;
  const int tid = threadIdx.x;

  for (int i = tid; i < 2561; i += 256) {
    float x;
    if (i < 384)       x = W1[i];
    else if (i < 448)  x = b1[i - 384];
    else if (i < 2496) x = W2[i - 448];
    else if (i < 2528) x = b2[i - 2496];
    else if (i < 2560) x = W3[i - 2528];
    else               x = b3[0];
    wl[i] = x;
  }
  __syncthreads();
  const float* W1L = wl;
  const float* b1L = wl + 384;
  const float* W2L = wl + 448;
  const float* b2L = wl + 2496;
  const float* W3L = wl + 2528;
  const float  b3s = wl[2560];

  int m = cnt[t];
  if (m > CAP) m = CAP;

  for (int i = tid; i < m; i += 256) {
    const int n = cand[(size_t)t * CAP + i];
    const size_t off = (size_t)n * 128 + t;
    float f[6];
    f[0] = 1.0f - fminf(p_th[off], 180.0f) / 180.0f;
    f[1] = 1.0f - fminf(p_xy[off], 800.0f) / 800.0f;
    f[2] = 1.0f - fminf(p_di[off], 800.0f) / 800.0f;
    f[3] = p_po[off]; f[4] = p_ne[off]; f[5] = p_io[off];

    float h1[64];
#pragma unroll
    for (int j = 0; j < 64; ++j) {
      float s = b1L[j];
#pragma unroll
      for (int k = 0; k < 6; ++k) s = fmaf(f[k], W1L[k * 64 + j], s);
      h1[j] = fmaxf(s, 0.0f);
    }
    float h2[32];
#pragma unroll
    for (int j = 0; j < 32; ++j) {
      float s = b2L[j];
#pragma unroll
      for (int k = 0; k < 64; ++k) s = fmaf(h1[k], W2L[k * 32 + j], s);
      h2[j] = fmaxf(s, 0.0f);
    }
    float lo = b3s;
#pragma unroll
    for (int k = 0; k < 32; ++k) lo = fmaf(h2[k], W3L[k], lo);
    const float sg = 1.0f / (1.0f + expf(-lo));
    ck[i]   = (sg < 0.5f) ? 0.0f : sg;
    cnid[i] = n;
  }
  __syncthreads();

  if (tid == 0) {
    float bv[8]; int bi[8];
#pragma unroll
    for (int q = 0; q < 8; ++q) { bv[q] = -1.0f; bi[q] = 0x7fffffff; }
    for (int i = 0; i < m; ++i) {
      const float x = ck[i];
      const int   n = cnid[i];
      if (x > bv[7] || (x == bv[7] && n < bi[7])) {
        int k = 7;
        while (k > 0 && (x > bv[k - 1] || (x == bv[k - 1] && n < bi[k - 1]))) {
          bv[k] = bv[k - 1]; bi[k] = bi[k - 1]; --k;
        }
        bv[k] = x; bi[k] = n;
      }
    }
#pragma unroll
    for (int q = 0; q < 8; ++q) {
      t8i[t * 8 + q] = bi[q];
      t8k[t * 8 + q] = bv[q];
    }
  }
}

// ---------------------------------------------------------------------------
// K4: order = stable descending argsort of targets[:,1]; assemble outputs.
// d_out (int32): rows[1024] | cols[1024] | valid[1024]
// ---------------------------------------------------------------------------
__global__ void k4_final(const float* __restrict__ targets,
                         const int* __restrict__ t8i, const float* __restrict__ t8k,
                         int* __restrict__ out)
{
  __shared__ float key[128];
  __shared__ int   ord[128];
  const int i = threadIdx.x;    // 0..127
  key[i] = targets[i * 4 + 1];
  __syncthreads();
  const float ki = key[i];
  int r = 0;
  for (int j = 0; j < 128; ++j) {
    const float kj = key[j];
    r += (kj > ki) || (kj == ki && j < i);
  }
  ord[r] = i;
  __syncthreads();
  const int src = ord[i];
#pragma unroll
  for (int k = 0; k < 8; ++k) {
    out[i * 8 + k]        = t8i[src * 8 + k];
    out[1024 + i * 8 + k] = src;
    out[2048 + i * 8 + k] = (t8k[src * 8 + k] > 0.0f) ? 1 : 0;
  }
}

// ---------------------------------------------------------------------------
extern "C" void kernel_launch(void* const* d_in, const int* in_sizes, int n_in,
                              void* d_out, int out_size, void* d_ws, size_t ws_size,
                              hipStream_t stream)
{
  const float* p_th = (const float*)d_in[0];
  const float* p_xy = (const float*)d_in[1];
  const float* p_di = (const float*)d_in[2];
  const float* p_po = (const float*)d_in[3];
  const float* p_ne = (const float*)d_in[4];
  const float* p_io = (const float*)d_in[5];
  const float* tgt  = (const float*)d_in[6];
  const float* W1   = (const float*)d_in[7];
  const float* b1   = (const float*)d_in[8];
  const float* W2   = (const float*)d_in[9];
  const float* b2   = (const float*)d_in[10];
  const float* W3   = (const float*)d_in[11];
  const float* b3   = (const float*)d_in[12];

  // workspace carve (~18.9 MB; pval and cand share a region, disjoint
  // lifetimes: pval dead after k2b, cand born in k2c)
  char* base = (char*)d_ws;
  u16*   lg   = (u16*)  (base);                 // 16,777,216 B
  float* pval = (float*)(base + 16777216);      //  1,048,576 B (k2a..k2b)
  int*   cand = (int*)  (base + 16777216);      //  2,097,152 B (k2c..k3)
  float* tau  = (float*)(base + 18874368);      //        512 B
  int*   cnt  = (int*)  (base + 18874880);      //        512 B
  int*   t8i  = (int*)  (base + 18875392);      //      4,096 B
  float* t8k  = (float*)(base + 18879488);      //      4,096 B

  hipMemsetAsync(cnt, 0, 128 * sizeof(int), stream);

  k1_mfma<<<2048, 256, 0, stream>>>(p_th, p_xy, p_di, p_po, p_ne, p_io,
                                    W1, b1, W2, b2, W3, b3, lg);
  k2a_part<<<256, 128, 0, stream>>>(lg, pval);
  k2b_merge<<<128, 64, 0, stream>>>(pval, tau);
  k2c_cand<<<256, 128, 0, stream>>>(lg, tau, cnt, cand);
  k3_refine<<<128, 256, 0, stream>>>(p_th, p_xy, p_di, p_po, p_ne, p_io,
                                     W1, b1, W2, b2, W3, b3,
                                     cnt, cand, t8i, t8k);
  k4_final<<<1, 128, 0, stream>>>(tgt, t8i, t8k, (int*)d_out);
}

// Round 5
// 689.729 us; speedup vs baseline: 1.5365x; 1.1942x over previous
//
#include <hip/hip_runtime.h>

// ---------------------------------------------------------------------------
// MatchNetAssign: 65536x128 pairs -> MLP(6->64->32->1) -> sigmoid -> clamp<0.5
// -> per-target top-8 -> reorder by argsort(-targets[:,1], stable).
// ROUND 5: K1 all-MFMA. Round 4 passed but K1's exact-L1 W1 table (96 f32)
// exceeded VGPR budget (VGPR_Count=88) -> per-iteration global reloads ->
// 280 us, MfmaUtil 5%. Now L1 is also 16x16x32 MFMA (feats+bias in k-slots
// 0..6 of quad 0); the C/D(row=4q+r) -> B(k=8q+j) layout bridge is 16 __shfl
// (in-register, per-lane src). All fragment layouts HW-confirmed by round 4.
// K2a/K2c widened to 512 blocks. K2b/K3/K4 frozen (passing since round 2).
// ---------------------------------------------------------------------------

typedef unsigned int   u32;
typedef unsigned short u16;
typedef short s8v  __attribute__((ext_vector_type(8)));   // 8 bf16 = 4 VGPR
typedef float f4v  __attribute__((ext_vector_type(4)));   // 16x16 accum

#define N_PROP   65536
#define N_TGT    128
#define N_PAIR   (N_PROP * N_TGT)      // 8388608
#define CAP      4096
#define MARGIN   0.15f
#define NCHUNK   512                   // K2a/K2c row-chunks (128 rows each)

static __device__ __forceinline__ u32 packbf(float a, float b) {
  // low16 = bf16_trunc(a), high16 = bf16_trunc(b)  (single v_perm_b32)
  return __builtin_amdgcn_perm(__float_as_uint(b), __float_as_uint(a), 0x07060302u);
}
static __device__ __forceinline__ float bf16_rne(float x) {
  u32 u = __float_as_uint(x);
  u = u + 0x7fffu + ((u >> 16) & 1u);
  return __uint_as_float(u & 0xffff0000u);
}
static __device__ __forceinline__ float bf2f(u16 u) {
  return __uint_as_float(((u32)u) << 16);
}
static __device__ __forceinline__ s8v mk_frag(u32 a, u32 b, u32 c, u32 d) {
  union { u32 u[4]; s8v v; } x;
  x.u[0] = a; x.u[1] = b; x.u[2] = c; x.u[3] = d;
  return x.v;
}
static __device__ __forceinline__ f4v MF16(s8v a, s8v b, f4v c) {
  return __builtin_amdgcn_mfma_f32_16x16x32_bf16(a, b, c, 0, 0, 0);
}

// ---------------------------------------------------------------------------
// K1: 16 pairs per wave-iteration, all three layers on the wave.
//  L1: h1-tile mt (units 16mt..16mt+15) = MF(aw1[mt], bfeat). A[m=lo4][k=8q+j]
//      = W1[k][16mt+lo4] (k<6), b1[16mt+lo4] (k==6), else 0. B[k=8q+j][n=lo4]
//      = feat k of pair lo4 (q==0 lanes only; bias 1.0 at k=6).
//  C/D gives lane(q,lo4) h1 units 16mt+4q+r of pair lo4. relu+pack ->
//  hl[mt] (units +0,+1), hh[mt] (units +2,+3).
//  Bridge to L2 B-layout (lane needs units 32c+8q+j): for chunk c, lane pulls
//  from quads a=2(q&1), a+1, register mt=2c+(q>>1): 8 shfl + 4 select per c.
//  L2: acc{0,1} = W2^T m-tiles (round-4-verified aw2). L3: per-lane partial
//  dot over its 8 h2 rows + butterfly over quads; q==0 writes bf16 logit.
// ---------------------------------------------------------------------------
__global__ __launch_bounds__(256) void k1_mfma(
    const float* __restrict__ p_th, const float* __restrict__ p_xy,
    const float* __restrict__ p_di, const float* __restrict__ p_po,
    const float* __restrict__ p_ne, const float* __restrict__ p_io,
    const float* __restrict__ W1, const float* __restrict__ b1,
    const float* __restrict__ W2, const float* __restrict__ b2,
    const float* __restrict__ W3, const float* __restrict__ b3,
    u16* __restrict__ lgout)
{
  const int tid = threadIdx.x;
  const int l   = tid & 63;
  const int lo4 = l & 15;
  const int q   = (l >> 4) & 3;

  // ---- A-frags for L1: W1^T m-tiles (k = 8q+j; nonzero only for q==0) ----
  s8v aw1[4];
#pragma unroll
  for (int mt = 0; mt < 4; ++mt) {
    float v[8];
#pragma unroll
    for (int j = 0; j < 8; ++j) {
      const int k = 8 * q + j;
      float x = 0.0f;
      if (k < 6)       x = W1[k * 64 + 16 * mt + lo4];
      else if (k == 6) x = b1[16 * mt + lo4];
      v[j] = bf16_rne(x);
    }
    aw1[mt] = mk_frag(packbf(v[0], v[1]), packbf(v[2], v[3]),
                      packbf(v[4], v[5]), packbf(v[6], v[7]));
  }

  // ---- A-frags for L2: W2^T (round-4-verified) ----
  s8v aw2[2][2];
#pragma unroll
  for (int mt = 0; mt < 2; ++mt)
#pragma unroll
    for (int c = 0; c < 2; ++c) {
      float v[8];
#pragma unroll
      for (int j = 0; j < 8; ++j)
        v[j] = bf16_rne(W2[(32 * c + 8 * q + j) * 32 + 16 * mt + lo4]);
      aw2[mt][c] = mk_frag(packbf(v[0], v[1]), packbf(v[2], v[3]),
                           packbf(v[4], v[5]), packbf(v[6], v[7]));
    }

  // ---- per-lane b2/W3 rows from C/D mapping (round-4-verified) ----
  float b2l[2][4], w3l[2][4];
#pragma unroll
  for (int mt = 0; mt < 2; ++mt)
#pragma unroll
    for (int r = 0; r < 4; ++r) {
      const int row = 16 * mt + 4 * q + r;
      b2l[mt][r] = b2[row];
      w3l[mt][r] = W3[row];
    }
  const float b3s = b3[0];
  const f4v Z4 = {};

  const bool q0  = (q == 0);
  const bool qlo = (q < 2);
  const int srcA = ((q & 1) << 5) + lo4;    // quad 2(q&1), same lo4
  const int srcB = srcA + 16;               // quad 2(q&1)+1

  const int nwaves = (gridDim.x * blockDim.x) >> 6;      // 8192
  const int w0 = (blockIdx.x * blockDim.x + tid) >> 6;
  const int NGRP = N_PAIR / 16;                          // 524288

  for (int g = w0; g < NGRP; g += nwaves) {
    const int idx = g * 16 + lo4;                        // this lane's pair
    const float x0 = p_th[idx], x1 = p_xy[idx], x2 = p_di[idx];
    const float x3 = p_po[idx], x4 = p_ne[idx], x5 = p_io[idx];
    const float f0 = fmaf(fminf(x0, 180.0f), -(1.0f / 180.0f), 1.0f);
    const float f1 = fmaf(fminf(x1, 800.0f), -(1.0f / 800.0f), 1.0f);
    const float f2 = fmaf(fminf(x2, 800.0f), -(1.0f / 800.0f), 1.0f);

    // B-frag for L1: feats in k-slots 0..5, bias 1.0 at k=6 (q==0 only)
    const s8v bfeat = mk_frag(q0 ? packbf(f0, f1) : 0u,
                              q0 ? packbf(f2, x3) : 0u,
                              q0 ? packbf(x4, x5) : 0u,
                              q0 ? 0x00003f80u : 0u);

    // ---- L1: 4 m-tiles of h1 ----
    u32 hl[4], hh[4];
#pragma unroll
    for (int mt = 0; mt < 4; ++mt) {
      const f4v hv = MF16(aw1[mt], bfeat, Z4);
      hl[mt] = packbf(fmaxf(hv[0], 0.0f), fmaxf(hv[1], 0.0f));
      hh[mt] = packbf(fmaxf(hv[2], 0.0f), fmaxf(hv[3], 0.0f));
    }

    // ---- bridge C/D -> B layout: chunk c needs units 32c+8q+j ----
    s8v b2f[2];
#pragma unroll
    for (int c = 0; c < 2; ++c) {
      const int mlo = 2 * c, mhi = 2 * c + 1;
      const u32 a0 = (u32)__shfl((int)hl[mlo], srcA, 64);
      const u32 a1 = (u32)__shfl((int)hh[mlo], srcA, 64);
      const u32 a2 = (u32)__shfl((int)hl[mlo], srcB, 64);
      const u32 a3 = (u32)__shfl((int)hh[mlo], srcB, 64);
      const u32 g0 = (u32)__shfl((int)hl[mhi], srcA, 64);
      const u32 g1 = (u32)__shfl((int)hh[mhi], srcA, 64);
      const u32 g2 = (u32)__shfl((int)hl[mhi], srcB, 64);
      const u32 g3 = (u32)__shfl((int)hh[mhi], srcB, 64);
      b2f[c] = mk_frag(qlo ? a0 : g0, qlo ? a1 : g1,
                       qlo ? a2 : g2, qlo ? a3 : g3);
    }

    // ---- L2: h2^T = W2^T . h1^T ----
    f4v acc0 = Z4, acc1 = Z4;
    acc0 = MF16(aw2[0][0], b2f[0], acc0);
    acc0 = MF16(aw2[0][1], b2f[1], acc0);
    acc1 = MF16(aw2[1][0], b2f[0], acc1);
    acc1 = MF16(aw2[1][1], b2f[1], acc1);

    // ---- L3: partial dot over this lane's 8 h2 rows, butterfly over quads --
    float part = 0.0f;
#pragma unroll
    for (int r = 0; r < 4; ++r) {
      part = fmaf(w3l[0][r], fmaxf(acc0[r] + b2l[0][r], 0.0f), part);
      part = fmaf(w3l[1][r], fmaxf(acc1[r] + b2l[1][r], 0.0f), part);
    }
    part += __shfl_xor(part, 16, 64);
    part += __shfl_xor(part, 32, 64);

    if (q0)
      lgout[idx] = (u16)(__float_as_uint(part + b3s) >> 16);
  }
}

// ---------------------------------------------------------------------------
// K2a: per-(chunk, target) top-8 approx values. NCHUNK blocks x 128 threads,
// each block covers 128 n rows; thread t tracks its target's top-8.
// ---------------------------------------------------------------------------
__global__ void k2a_part(const u16* __restrict__ lg, float* __restrict__ pval)
{
  const int t = threadIdx.x;       // 0..127
  const int c = blockIdx.x;        // 0..NCHUNK-1
  const size_t base = (size_t)c * 128 * 128 + t;
  float v[8];
#pragma unroll
  for (int q = 0; q < 8; ++q) v[q] = -3.4e38f;
#pragma unroll 4
  for (int i = 0; i < 128; ++i) {
    const float x = bf2f(lg[base + (size_t)i * 128]);
    if (x > v[7]) {
      int k = 7;
      while (k > 0 && x > v[k - 1]) { v[k] = v[k - 1]; --k; }
      v[k] = x;
    }
  }
  float* o = pval + ((size_t)c * 128 + t) * 8;
#pragma unroll
  for (int q = 0; q < 8; ++q) o[q] = v[q];
}

// K2b: merge NCHUNK partials per target -> tau[t] = (8th approx) - MARGIN.
__global__ void k2b_merge(const float* __restrict__ pval, float* __restrict__ tau)
{
  __shared__ float sm[64 * 8];
  const int t = blockIdx.x;
  const int i = threadIdx.x;       // 0..63
  float v[8];
#pragma unroll
  for (int q = 0; q < 8; ++q) v[q] = -3.4e38f;
  for (int e = i; e < NCHUNK * 8; e += 64) {
    const float x = pval[(size_t)(e >> 3) * 1024 + (size_t)t * 8 + (e & 7)];
    if (x > v[7]) {
      int k = 7;
      while (k > 0 && x > v[k - 1]) { v[k] = v[k - 1]; --k; }
      v[k] = x;
    }
  }
#pragma unroll
  for (int q = 0; q < 8; ++q) sm[i * 8 + q] = v[q];
  __syncthreads();
  if (i == 0) {
    float w[8];
#pragma unroll
    for (int q = 0; q < 8; ++q) w[q] = -3.4e38f;
    for (int e = 0; e < 512; ++e) {
      const float x = sm[e];
      if (x > w[7]) {
        int k = 7;
        while (k > 0 && x > w[k - 1]) { w[k] = w[k - 1]; --k; }
        w[k] = x;
      }
    }
    tau[t] = w[7] - MARGIN;
  }
}

// K2c: collect candidates: approx >= tau, plus forced n<16 (zero-fill ties).
__global__ void k2c_cand(const u16* __restrict__ lg, const float* __restrict__ tau,
                         int* __restrict__ cnt, int* __restrict__ cand)
{
  const int t = threadIdx.x;
  const int c = blockIdx.x;
  const int n0 = c * 128;
  const float ta = tau[t];
  for (int i = 0; i < 128; ++i) {
    const int n = n0 + i;
    const float x = bf2f(lg[(size_t)n * 128 + t]);
    if (x >= ta || n < 16) {
      const int p = atomicAdd(&cnt[t], 1);
      if (p < CAP) cand[(size_t)t * CAP + p] = n;
    }
  }
}

// ---------------------------------------------------------------------------
// K3: exact f32 refine of candidates + per-target top-8 with exact ref
// semantics: key = (sigmoid < 0.5 ? 0 : sigmoid), order (key desc, idx asc).
// ---------------------------------------------------------------------------
__global__ __launch_bounds__(256) void k3_refine(
    const float* __restrict__ p_th, const float* __restrict__ p_xy,
    const float* __restrict__ p_di, const float* __restrict__ p_po,
    const float* __restrict__ p_ne, const float* __restrict__ p_io,
    const float* __restrict__ W1, const float* __restrict__ b1,
    const float* __restrict__ W2, const float* __restrict__ b2,
    const float* __restrict__ W3, const float* __restrict__ b3,
    const int* __restrict__ cnt, const int* __restrict__ cand,
    int* __restrict__ t8i, float* __restrict__ t8k)
{
  __shared__ float wl[2561];
  __shared__ float ck[CAP];
  __shared__ int   cnid[CAP];
  const int t = blockIdx.x;
  const int tid = threadIdx.x;

  for (int i = tid; i < 2561; i += 256) {
    float x;
    if (i < 384)       x = W1[i];
    else if (i < 448)  x = b1[i - 384];
    else if (i < 2496) x = W2[i - 448];
    else if (i < 2528) x = b2[i - 2496];
    else if (i < 2560) x = W3[i - 2528];
    else               x = b3[0];
    wl[i] = x;
  }
  __syncthreads();
  const float* W1L = wl;
  const float* b1L = wl + 384;
  const float* W2L = wl + 448;
  const float* b2L = wl + 2496;
  const float* W3L = wl + 2528;
  const float  b3s = wl[2560];

  int m = cnt[t];
  if (m > CAP) m = CAP;

  for (int i = tid; i < m; i += 256) {
    const int n = cand[(size_t)t * CAP + i];
    const size_t off = (size_t)n * 128 + t;
    float f[6];
    f[0] = 1.0f - fminf(p_th[off], 180.0f) / 180.0f;
    f[1] = 1.0f - fminf(p_xy[off], 800.0f) / 800.0f;
    f[2] = 1.0f - fminf(p_di[off], 800.0f) / 800.0f;
    f[3] = p_po[off]; f[4] = p_ne[off]; f[5] = p_io[off];

    float h1[64];
#pragma unroll
    for (int j = 0; j < 64; ++j) {
      float s = b1L[j];
#pragma unroll
      for (int k = 0; k < 6; ++k) s = fmaf(f[k], W1L[k * 64 + j], s);
      h1[j] = fmaxf(s, 0.0f);
    }
    float h2[32];
#pragma unroll
    for (int j = 0; j < 32; ++j) {
      float s = b2L[j];
#pragma unroll
      for (int k = 0; k < 64; ++k) s = fmaf(h1[k], W2L[k * 32 + j], s);
      h2[j] = fmaxf(s, 0.0f);
    }
    float lo = b3s;
#pragma unroll
    for (int k = 0; k < 32; ++k) lo = fmaf(h2[k], W3L[k], lo);
    const float sg = 1.0f / (1.0f + expf(-lo));
    ck[i]   = (sg < 0.5f) ? 0.0f : sg;
    cnid[i] = n;
  }
  __syncthreads();

  if (tid == 0) {
    float bv[8]; int bi[8];
#pragma unroll
    for (int q = 0; q < 8; ++q) { bv[q] = -1.0f; bi[q] = 0x7fffffff; }
    for (int i = 0; i < m; ++i) {
      const float x = ck[i];
      const int   n = cnid[i];
      if (x > bv[7] || (x == bv[7] && n < bi[7])) {
        int k = 7;
        while (k > 0 && (x > bv[k - 1] || (x == bv[k - 1] && n < bi[k - 1]))) {
          bv[k] = bv[k - 1]; bi[k] = bi[k - 1]; --k;
        }
        bv[k] = x; bi[k] = n;
      }
    }
#pragma unroll
    for (int q = 0; q < 8; ++q) {
      t8i[t * 8 + q] = bi[q];
      t8k[t * 8 + q] = bv[q];
    }
  }
}

// ---------------------------------------------------------------------------
// K4: order = stable descending argsort of targets[:,1]; assemble outputs.
// d_out (int32): rows[1024] | cols[1024] | valid[1024]
// ---------------------------------------------------------------------------
__global__ void k4_final(const float* __restrict__ targets,
                         const int* __restrict__ t8i, const float* __restrict__ t8k,
                         int* __restrict__ out)
{
  __shared__ float key[128];
  __shared__ int   ord[128];
  const int i = threadIdx.x;    // 0..127
  key[i] = targets[i * 4 + 1];
  __syncthreads();
  const float ki = key[i];
  int r = 0;
  for (int j = 0; j < 128; ++j) {
    const float kj = key[j];
    r += (kj > ki) || (kj == ki && j < i);
  }
  ord[r] = i;
  __syncthreads();
  const int src = ord[i];
#pragma unroll
  for (int k = 0; k < 8; ++k) {
    out[i * 8 + k]        = t8i[src * 8 + k];
    out[1024 + i * 8 + k] = src;
    out[2048 + i * 8 + k] = (t8k[src * 8 + k] > 0.0f) ? 1 : 0;
  }
}

// ---------------------------------------------------------------------------
extern "C" void kernel_launch(void* const* d_in, const int* in_sizes, int n_in,
                              void* d_out, int out_size, void* d_ws, size_t ws_size,
                              hipStream_t stream)
{
  const float* p_th = (const float*)d_in[0];
  const float* p_xy = (const float*)d_in[1];
  const float* p_di = (const float*)d_in[2];
  const float* p_po = (const float*)d_in[3];
  const float* p_ne = (const float*)d_in[4];
  const float* p_io = (const float*)d_in[5];
  const float* tgt  = (const float*)d_in[6];
  const float* W1   = (const float*)d_in[7];
  const float* b1   = (const float*)d_in[8];
  const float* W2   = (const float*)d_in[9];
  const float* b2   = (const float*)d_in[10];
  const float* W3   = (const float*)d_in[11];
  const float* b3   = (const float*)d_in[12];

  // workspace carve (~18.9 MB; pval and cand share a 2 MB region, disjoint
  // lifetimes: pval dead after k2b, cand born in k2c)
  char* base = (char*)d_ws;
  u16*   lg   = (u16*)  (base);                 // 16,777,216 B
  float* pval = (float*)(base + 16777216);      //  2,097,152 B (k2a..k2b)
  int*   cand = (int*)  (base + 16777216);      //  2,097,152 B (k2c..k3)
  float* tau  = (float*)(base + 18874368);      //        512 B
  int*   cnt  = (int*)  (base + 18874880);      //        512 B
  int*   t8i  = (int*)  (base + 18875392);      //      4,096 B
  float* t8k  = (float*)(base + 18879488);      //      4,096 B

  hipMemsetAsync(cnt, 0, 128 * sizeof(int), stream);

  k1_mfma<<<2048, 256, 0, stream>>>(p_th, p_xy, p_di, p_po, p_ne, p_io,
                                    W1, b1, W2, b2, W3, b3, lg);
  k2a_part<<<NCHUNK, 128, 0, stream>>>(lg, pval);
  k2b_merge<<<128, 64, 0, stream>>>(pval, tau);
  k2c_cand<<<NCHUNK, 128, 0, stream>>>(lg, tau, cnt, cand);
  k3_refine<<<128, 256, 0, stream>>>(p_th, p_xy, p_di, p_po, p_ne, p_io,
                                     W1, b1, W2, b2, W3, b3,
                                     cnt, cand, t8i, t8k);
  k4_final<<<1, 128, 0, stream>>>(tgt, t8i, t8k, (int*)d_out);
}